// Round 2
// baseline (1747.520 us; speedup 1.0000x reference)
//
#include <hip/hip_runtime.h>
#include <hip/hip_bf16.h>

// ---------------------------------------------------------------------------
// VQ-VAE QNetwork forward, fp32 throughout (VQ argmin must match np fp32).
// Layouts all NCHW-flat. B=1024.
//   h1  [B,32,21,21]   h2 [B,64,10,10]  enc [B,64,8,8]  quant [B,64,8,8]
//   d1  [B,64,10,10]   d2 [B,32,21,21]  hidden [B,512]
// ---------------------------------------------------------------------------

#define ENC_SCALE (1.0f/65025.0f)   // (x/255)/255

__global__ __launch_bounds__(256) void zero_k(float* __restrict__ hidden,
                                              float* __restrict__ accum) {
  int t = blockIdx.x * 256 + threadIdx.x;
  if (t < 524288) hidden[t] = 0.f;
  if (t < 8) accum[t] = 0.f;
}

// ---- conv1: [B,4,84,84] -> [B,32,21,21], k4 s4, scale 1/255^2, relu -------
__global__ __launch_bounds__(256) void conv1_k(
    const float* __restrict__ x, const float* __restrict__ w1,
    const float* __restrict__ b1, float* __restrict__ out) {
  int lane = threadIdx.x & 63;
  int wv = __builtin_amdgcn_readfirstlane(threadIdx.x >> 6);
  int oc0 = wv * 8;                        // 4 waves -> 32 oc
  int p = blockIdx.x * 64 + lane;          // 451584 pixels
  int b = p / 441, rem = p % 441;
  int oy = rem / 21, ox = rem % 21;
  const float* xb = x + (long)b * 28224 + (oy * 4) * 84 + ox * 4;
  const float* wp = w1 + oc0 * 64;
  float acc[8];
  #pragma unroll
  for (int c = 0; c < 8; ++c) acc[c] = b1[oc0 + c];
  #pragma unroll 1
  for (int i = 0; i < 4; ++i)
    #pragma unroll
    for (int ky = 0; ky < 4; ++ky)
      #pragma unroll
      for (int kx = 0; kx < 4; ++kx) {
        float v = xb[i * 7056 + ky * 84 + kx] * ENC_SCALE;
        int t = i * 16 + ky * 4 + kx;
        #pragma unroll
        for (int c = 0; c < 8; ++c)
          acc[c] = fmaf(v, wp[c * 64 + t], acc[c]);
      }
  float* ob = out + ((long)b * 32 + oc0) * 441 + rem;
  #pragma unroll
  for (int c = 0; c < 8; ++c) ob[c * 441] = fmaxf(acc[c], 0.f);
}

// ---- conv2: [B,32,21,21] -> [B,64,10,10], k3 s2, relu ---------------------
__global__ __launch_bounds__(256) void conv2_k(
    const float* __restrict__ in, const float* __restrict__ w,
    const float* __restrict__ bias, float* __restrict__ out) {
  int lane = threadIdx.x & 63;
  int wv = __builtin_amdgcn_readfirstlane(threadIdx.x >> 6);
  int oc0 = blockIdx.y * 32 + wv * 8;      // grid.y=2 -> 64 oc
  int p = blockIdx.x * 64 + lane;          // 102400 pixels
  int b = p / 100, rem = p % 100;
  int oy = rem / 10, ox = rem % 10;
  const float* ib = in + (long)b * 14112 + (oy * 2) * 21 + ox * 2;
  const float* wp = w + oc0 * 288;
  float acc[8];
  #pragma unroll
  for (int c = 0; c < 8; ++c) acc[c] = bias[oc0 + c];
  #pragma unroll 2
  for (int i = 0; i < 32; ++i)
    #pragma unroll
    for (int ky = 0; ky < 3; ++ky)
      #pragma unroll
      for (int kx = 0; kx < 3; ++kx) {
        float v = ib[i * 441 + ky * 21 + kx];
        int t = i * 9 + ky * 3 + kx;
        #pragma unroll
        for (int c = 0; c < 8; ++c)
          acc[c] = fmaf(v, wp[c * 288 + t], acc[c]);
      }
  float* ob = out + ((long)b * 64 + oc0) * 100 + rem;
  #pragma unroll
  for (int c = 0; c < 8; ++c) ob[c * 100] = fmaxf(acc[c], 0.f);
}

// ---- conv3: [B,64,10,10] -> [B,64,8,8], k3 s1, relu -----------------------
__global__ __launch_bounds__(256) void conv3_k(
    const float* __restrict__ in, const float* __restrict__ w,
    const float* __restrict__ bias, float* __restrict__ out) {
  int lane = threadIdx.x & 63;
  int wv = __builtin_amdgcn_readfirstlane(threadIdx.x >> 6);
  int oc0 = blockIdx.y * 32 + wv * 8;
  int p = blockIdx.x * 64 + lane;          // 65536 pixels
  int b = p >> 6, rem = p & 63;
  int oy = rem >> 3, ox = rem & 7;
  const float* ib = in + (long)b * 6400 + oy * 10 + ox;
  const float* wp = w + oc0 * 576;
  float acc[8];
  #pragma unroll
  for (int c = 0; c < 8; ++c) acc[c] = bias[oc0 + c];
  #pragma unroll 2
  for (int i = 0; i < 64; ++i)
    #pragma unroll
    for (int ky = 0; ky < 3; ++ky)
      #pragma unroll
      for (int kx = 0; kx < 3; ++kx) {
        float v = ib[i * 100 + ky * 10 + kx];
        int t = i * 9 + ky * 3 + kx;
        #pragma unroll
        for (int c = 0; c < 8; ++c)
          acc[c] = fmaf(v, wp[c * 576 + t], acc[c]);
      }
  float* ob = out + ((long)b * 64 + oc0) * 64 + rem;
  #pragma unroll
  for (int c = 0; c < 8; ++c) ob[c * 64] = fmaxf(acc[c], 0.f);
}

// ---- VQ: argmin over 512 codes, write quant = emb[idx], accumulate loss ---
// Block b handles all 64 positions of image b. 8 rows x 8 codes register tile.
__global__ __launch_bounds__(256) void vq_k(
    const float* __restrict__ enc, const float* __restrict__ emb,
    float* __restrict__ quant, float* __restrict__ accum) {
  __shared__ float elT[64 * 516];    // e^T, padded: elT[d*516 + k]  (132 KB)
  __shared__ float qT[64 * 36];      // qT[d*36 + r], r<32 rows/pass (9 KB)
  __shared__ float qq_s[32];
  __shared__ float ee_s[512];

  int tid = threadIdx.x;
  int b = blockIdx.x;
  int lane = tid & 63;
  int w = tid >> 6;

  for (int s = tid; s < 512 * 64; s += 256) {
    int k = s >> 6, d = s & 63;
    elT[d * 516 + k] = emb[s];
  }
  __syncthreads();
  for (int kk = tid; kk < 512; kk += 256) {
    float s = 0.f;
    for (int d = 0; d < 64; ++d) { float e = elT[d * 516 + kk]; s = fmaf(e, e, s); }
    ee_s[kk] = s;
  }
  __syncthreads();
  float eer[8];
  #pragma unroll
  for (int j = 0; j < 2; ++j)
    #pragma unroll
    for (int c = 0; c < 4; ++c) eer[j * 4 + c] = ee_s[j * 256 + lane * 4 + c];

  float lossacc = 0.f;
  for (int pass = 0; pass < 2; ++pass) {
    int l0 = pass * 32;
    __syncthreads();
    for (int s = tid; s < 2048; s += 256) {
      int r = s & 31, d = s >> 5;
      qT[d * 36 + r] = enc[((b * 64 + d) << 6) + l0 + r];
    }
    __syncthreads();
    if (tid < 32) {
      float s = 0.f;
      for (int d = 0; d < 64; ++d) { float v = qT[d * 36 + tid]; s = fmaf(v, v, s); }
      qq_s[tid] = s;
    }
    __syncthreads();

    int r0 = w * 8;
    float dot[8][8] = {};
    #pragma unroll 2
    for (int d = 0; d < 64; ++d) {
      float4 e0 = *(const float4*)&elT[d * 516 + lane * 4];
      float4 e1 = *(const float4*)&elT[d * 516 + 256 + lane * 4];
      float4 q0 = *(const float4*)&qT[d * 36 + r0];
      float4 q1 = *(const float4*)&qT[d * 36 + r0 + 4];
      float qv[8] = {q0.x, q0.y, q0.z, q0.w, q1.x, q1.y, q1.z, q1.w};
      float ev[8] = {e0.x, e0.y, e0.z, e0.w, e1.x, e1.y, e1.z, e1.w};
      #pragma unroll
      for (int r = 0; r < 8; ++r)
        #pragma unroll
        for (int je = 0; je < 8; ++je)
          dot[r][je] = fmaf(qv[r], ev[je], dot[r][je]);
    }

    #pragma unroll 1
    for (int r = 0; r < 8; ++r) {
      float best = 1e30f; int bk = 0;
      #pragma unroll
      for (int je = 0; je < 8; ++je) {
        float sc = fmaf(-2.f, dot[r][je], eer[je]);
        int k = (je >> 2) * 256 + lane * 4 + (je & 3);
        if (sc < best || (sc == best && k < bk)) { best = sc; bk = k; }
      }
      #pragma unroll
      for (int off = 32; off; off >>= 1) {
        float ob = __shfl_xor(best, off);
        int ok = __shfl_xor(bk, off);
        if (ob < best || (ob == best && ok < bk)) { best = ob; bk = ok; }
      }
      int l = l0 + r0 + r;
      quant[((b << 6) + lane) * 64 + l] = emb[bk * 64 + lane];
      if (lane == 0) lossacc += qq_s[r0 + r] + best;
    }
  }
  if (lane == 0) atomicAdd(accum + 1, lossacc);
}

// ---- deconv1: [B,64,8,8] -> [B,64,10,10], k3 s1 pad2(full), relu ----------
__global__ __launch_bounds__(256) void dec1_k(
    const float* __restrict__ in, const float* __restrict__ w,
    const float* __restrict__ bias, float* __restrict__ out) {
  int lane = threadIdx.x & 63;
  int wv = __builtin_amdgcn_readfirstlane(threadIdx.x >> 6);
  int oc0 = blockIdx.y * 32 + wv * 8;
  int p = blockIdx.x * 64 + lane;          // 102400 pixels
  int b = p / 100, rem = p % 100;
  int oy = rem / 10, ox = rem % 10;
  const float* ib = in + (long)b * 4096;
  const float* wp = w + oc0 * 576;
  float acc[8];
  #pragma unroll
  for (int cc = 0; cc < 8; ++cc) acc[cc] = bias[oc0 + cc];
  for (int ky = 0; ky < 3; ++ky) {
    int iy = oy + ky - 2;
    if ((unsigned)iy >= 8u) continue;
    for (int kx = 0; kx < 3; ++kx) {
      int ix = ox + kx - 2;
      if ((unsigned)ix >= 8u) continue;
      const float* wt = wp + ky * 3 + kx;
      const float* ibt = ib + iy * 8 + ix;
      #pragma unroll 2
      for (int i = 0; i < 64; ++i) {
        float v = ibt[i * 64];
        #pragma unroll
        for (int cc = 0; cc < 8; ++cc)
          acc[cc] = fmaf(v, wt[cc * 576 + i * 9], acc[cc]);
      }
    }
  }
  float* ob = out + ((long)b * 64 + oc0) * 100 + rem;
  #pragma unroll
  for (int cc = 0; cc < 8; ++cc) ob[cc * 100] = fmaxf(acc[cc], 0.f);
}

// ---- deconv2: [B,64,10,10] -> [B,32,21,21], k3 s2, relu; 4 parity classes -
__global__ __launch_bounds__(256) void dec2_k(
    const float* __restrict__ in, const float* __restrict__ w,
    const float* __restrict__ bias, float* __restrict__ out) {
  int lane = threadIdx.x & 63;
  int wv = __builtin_amdgcn_readfirstlane(threadIdx.x >> 6);
  int oc0 = wv * 8;                        // 32 oc
  int cls = blockIdx.y;                    // parity class
  int a = cls >> 1, c = cls & 1;
  int U = a ? 10 : 11, V = c ? 10 : 11;
  int b = blockIdx.x >> 1;
  int p = (blockIdx.x & 1) * 64 + lane;
  if (p >= U * V) return;
  int u = p / V, v = p % V;
  int oy = 2 * u + a, ox = 2 * v + c;
  int ny = a ? 1 : 2, nx = c ? 1 : 2;
  int iyb = a ? u : u - 1, ixb = c ? v : v - 1;
  int kyb = a ? 1 : 0, kxb = c ? 1 : 0;
  const float* ib = in + (long)b * 6400;
  const float* wp = w + oc0 * 576;
  float acc[8];
  #pragma unroll
  for (int cc = 0; cc < 8; ++cc) acc[cc] = bias[oc0 + cc];
  for (int ty = 0; ty < ny; ++ty) {
    int iy = iyb + ty;
    if ((unsigned)iy >= 10u) continue;
    int ky = kyb + 2 * ty;
    for (int tx = 0; tx < nx; ++tx) {
      int ix = ixb + tx;
      if ((unsigned)ix >= 10u) continue;
      int kx = kxb + 2 * tx;
      const float* wt = wp + ky * 3 + kx;
      const float* ibt = ib + iy * 10 + ix;
      #pragma unroll 2
      for (int i = 0; i < 64; ++i) {
        float vv = ibt[i * 100];
        #pragma unroll
        for (int cc = 0; cc < 8; ++cc)
          acc[cc] = fmaf(vv, wt[cc * 576 + i * 9], acc[cc]);
      }
    }
  }
  float* ob = out + ((long)b * 32 + oc0) * 441 + oy * 21 + ox;
  #pragma unroll
  for (int cc = 0; cc < 8; ++cc) ob[cc * 441] = fmaxf(acc[cc], 0.f);
}

// ---- deconv3 + sigmoid + rec-loss: [B,32,21,21] -> loss vs x/255 ----------
__global__ __launch_bounds__(256) void dec3_k(
    const float* __restrict__ d2, const float* __restrict__ dw3,
    const float* __restrict__ db3, const float* __restrict__ x,
    float* __restrict__ accum) {
  int lane = threadIdx.x & 63;
  int wv = threadIdx.x >> 6;
  long t = (long)blockIdx.x * 256 + threadIdx.x;   // B*84*84 = 7225344 px
  int b = (int)(t / 7056), rem = (int)(t % 7056);
  int y = rem / 84, xc = rem % 84;
  int ky = (3 - (y & 3)) & 3;
  int kx = (3 - (xc & 3)) & 3;
  int iy = (y + ky - 3) >> 2;
  int ix = (xc + kx - 3) >> 2;
  const float* ib = d2 + (long)b * 14112 + iy * 21 + ix;
  float acc[4];
  #pragma unroll
  for (int c = 0; c < 4; ++c) acc[c] = db3[c];
  #pragma unroll 4
  for (int i = 0; i < 32; ++i) {
    float v = ib[i * 441];
    #pragma unroll
    for (int c = 0; c < 4; ++c)
      acc[c] = fmaf(v, dw3[(c * 32 + i) * 16 + ky * 4 + kx], acc[c]);
  }
  float ls = 0.f;
  #pragma unroll
  for (int c = 0; c < 4; ++c) {
    float dec = 1.f / (1.f + __expf(-acc[c]));
    float xv = x[((long)b * 4 + c) * 7056 + rem] * (1.f / 255.f);
    float df = dec - xv;
    ls = fmaf(df, df, ls);
  }
  #pragma unroll
  for (int off = 32; off; off >>= 1) ls += __shfl_down(ls, off);
  __shared__ float r4[4];
  if (lane == 0) r4[wv] = ls;
  __syncthreads();
  if (threadIdx.x == 0) atomicAdd(accum, r4[0] + r4[1] + r4[2] + r4[3]);
}

// ---- FC1: hidden += quant_flat @ lw1 (k-split 4, 16-batch regs, atomics) --
__global__ __launch_bounds__(256) void fc1_k(
    const float* __restrict__ quant, const float* __restrict__ lw1,
    float* __restrict__ hidden) {
  int n = (blockIdx.x & 1) * 256 + threadIdx.x;
  int bg = (blockIdx.x >> 1) & 63;
  int ks = blockIdx.x >> 7;                // 0..3
  int b0 = bg * 16;
  const float* q0 = quant + (long)b0 * 4096 + ks * 1024;
  const float* w0 = lw1 + (long)ks * 1024 * 512 + n;
  float acc[16] = {};
  #pragma unroll 4
  for (int k = 0; k < 1024; ++k) {
    float wvv = w0[(long)k * 512];
    #pragma unroll
    for (int bb = 0; bb < 16; ++bb)
      acc[bb] = fmaf(q0[bb * 4096 + k], wvv, acc[bb]);
  }
  #pragma unroll
  for (int bb = 0; bb < 16; ++bb)
    atomicAdd(&hidden[(b0 + bb) * 512 + n], acc[bb]);
}

// ---- FC2: q_values = relu(hidden + lb1) @ lw2 + lb2; write losses ---------
__global__ __launch_bounds__(256) void fc2_k(
    const float* __restrict__ hidden, const float* __restrict__ lb1,
    const float* __restrict__ lw2, const float* __restrict__ lb2,
    const float* __restrict__ accum, float* __restrict__ out) {
  int t = blockIdx.x * 256 + threadIdx.x;  // 18432
  int b = t / 18, a = t % 18;
  const float* h = hidden + b * 512;
  float acc = lb2[a];
  #pragma unroll 4
  for (int n = 0; n < 512; ++n) {
    float hv = fmaxf(h[n] + lb1[n], 0.f);
    acc = fmaf(hv, lw2[n * 18 + a], acc);
  }
  out[t] = acc;
  if (t == 0) {
    out[18432] = accum[0] * (1.f / 28901376.f);          // /(1024*4*84*84)
    out[18433] = 1.25f * accum[1] * (1.f / 4194304.f);   // /(65536*64)
  }
}

extern "C" void kernel_launch(void* const* d_in, const int* in_sizes, int n_in,
                              void* d_out, int out_size, void* d_ws, size_t ws_size,
                              hipStream_t stream) {
  const float* x   = (const float*)d_in[0];
  const float* w1  = (const float*)d_in[1];
  const float* b1  = (const float*)d_in[2];
  const float* w2  = (const float*)d_in[3];
  const float* b2  = (const float*)d_in[4];
  const float* w3  = (const float*)d_in[5];
  const float* b3  = (const float*)d_in[6];
  const float* emb = (const float*)d_in[7];
  const float* dw1 = (const float*)d_in[8];
  const float* db1 = (const float*)d_in[9];
  const float* dw2 = (const float*)d_in[10];
  const float* db2 = (const float*)d_in[11];
  const float* dw3 = (const float*)d_in[12];
  const float* db3 = (const float*)d_in[13];
  const float* lw1 = (const float*)d_in[14];
  const float* lb1 = (const float*)d_in[15];
  const float* lw2 = (const float*)d_in[16];
  const float* lb2 = (const float*)d_in[17];

  float* ws = (float*)d_ws;
  float* h1     = ws;                    // 14450688 floats [B,32,21,21]
  float* h2     = ws + 14450688;         //  6553600 floats [B,64,10,10]
  float* enc    = ws + 21004288;         //  4194304 floats [B,64,8,8]
  float* quant  = ws + 25198592;         //  4194304 floats [B,64,8,8]
  float* d1     = h2;                    // reuse (h2 dead after conv3)
  float* d2b    = h1;                    // reuse (h1 dead after conv2)
  float* hidden = ws + 29392896;         //   524288 floats [B,512]
  float* accum  = ws + 29917184;         // [0]=rec sum, [1]=quant sum
  float* outp   = (float*)d_out;

  zero_k<<<2048, 256, 0, stream>>>(hidden, accum);
  conv1_k<<<dim3(7056, 1), 256, 0, stream>>>(x, w1, b1, h1);
  conv2_k<<<dim3(1600, 2), 256, 0, stream>>>(h1, w2, b2, h2);
  conv3_k<<<dim3(1024, 2), 256, 0, stream>>>(h2, w3, b3, enc);
  vq_k<<<1024, 256, 0, stream>>>(enc, emb, quant, accum);
  dec1_k<<<dim3(1600, 2), 256, 0, stream>>>(quant, dw1, db1, d1);
  dec2_k<<<dim3(2048, 4), 256, 0, stream>>>(d1, dw2, db2, d2b);
  dec3_k<<<28224, 256, 0, stream>>>(d2b, dw3, db3, x, accum);
  fc1_k<<<512, 256, 0, stream>>>(quant, lw1, hidden);
  fc2_k<<<72, 256, 0, stream>>>(hidden, lb1, lw2, lb2, accum, outp);
}

// Round 3
// 1410.993 us; speedup vs baseline: 1.2385x; 1.2385x over previous
//
#include <hip/hip_runtime.h>
#include <hip/hip_bf16.h>

// ---------------------------------------------------------------------------
// VQ-VAE QNetwork forward, fp32 throughout (VQ argmin must match np fp32).
// Layouts all NCHW-flat. B=1024.
//   h1  [B,32,21,21]   h2 [B,64,10,10]  enc [B,64,8,8]  quant [B,64,8,8]
//   d1  [B,64,10,10]   d2 [B,32,21,21]  hidden [B,512]
// ---------------------------------------------------------------------------

#define ENC_SCALE (1.0f/65025.0f)   // (x/255)/255

__global__ __launch_bounds__(256) void zero_k(float* __restrict__ hidden,
                                              float* __restrict__ accum) {
  int t = blockIdx.x * 256 + threadIdx.x;
  if (t < 524288) hidden[t] = 0.f;
  if (t < 8) accum[t] = 0.f;
}

// ---- conv1: [B,4,84,84] -> [B,32,21,21], k4 s4, scale 1/255^2, relu -------
__global__ __launch_bounds__(256) void conv1_k(
    const float* __restrict__ x, const float* __restrict__ w1,
    const float* __restrict__ b1, float* __restrict__ out) {
  int lane = threadIdx.x & 63;
  int wv = __builtin_amdgcn_readfirstlane(threadIdx.x >> 6);
  int oc0 = wv * 8;                        // 4 waves -> 32 oc
  int p = blockIdx.x * 64 + lane;          // 451584 pixels
  int b = p / 441, rem = p % 441;
  int oy = rem / 21, ox = rem % 21;
  const float* xb = x + (long)b * 28224 + (oy * 4) * 84 + ox * 4;
  const float* wp = w1 + oc0 * 64;
  float acc[8];
  #pragma unroll
  for (int c = 0; c < 8; ++c) acc[c] = b1[oc0 + c];
  #pragma unroll 1
  for (int i = 0; i < 4; ++i)
    #pragma unroll
    for (int ky = 0; ky < 4; ++ky)
      #pragma unroll
      for (int kx = 0; kx < 4; ++kx) {
        float v = xb[i * 7056 + ky * 84 + kx] * ENC_SCALE;
        int t = i * 16 + ky * 4 + kx;
        #pragma unroll
        for (int c = 0; c < 8; ++c)
          acc[c] = fmaf(v, wp[c * 64 + t], acc[c]);
      }
  float* ob = out + ((long)b * 32 + oc0) * 441 + rem;
  #pragma unroll
  for (int c = 0; c < 8; ++c) ob[c * 441] = fmaxf(acc[c], 0.f);
}

// ---- conv2: [B,32,21,21] -> [B,64,10,10], k3 s2, relu ---------------------
__global__ __launch_bounds__(256) void conv2_k(
    const float* __restrict__ in, const float* __restrict__ w,
    const float* __restrict__ bias, float* __restrict__ out) {
  int lane = threadIdx.x & 63;
  int wv = __builtin_amdgcn_readfirstlane(threadIdx.x >> 6);
  int oc0 = blockIdx.y * 32 + wv * 8;      // grid.y=2 -> 64 oc
  int p = blockIdx.x * 64 + lane;          // 102400 pixels
  int b = p / 100, rem = p % 100;
  int oy = rem / 10, ox = rem % 10;
  const float* ib = in + (long)b * 14112 + (oy * 2) * 21 + ox * 2;
  const float* wp = w + oc0 * 288;
  float acc[8];
  #pragma unroll
  for (int c = 0; c < 8; ++c) acc[c] = bias[oc0 + c];
  #pragma unroll 2
  for (int i = 0; i < 32; ++i)
    #pragma unroll
    for (int ky = 0; ky < 3; ++ky)
      #pragma unroll
      for (int kx = 0; kx < 3; ++kx) {
        float v = ib[i * 441 + ky * 21 + kx];
        int t = i * 9 + ky * 3 + kx;
        #pragma unroll
        for (int c = 0; c < 8; ++c)
          acc[c] = fmaf(v, wp[c * 288 + t], acc[c]);
      }
  float* ob = out + ((long)b * 64 + oc0) * 100 + rem;
  #pragma unroll
  for (int c = 0; c < 8; ++c) ob[c * 100] = fmaxf(acc[c], 0.f);
}

// ---- conv3: [B,64,10,10] -> [B,64,8,8], k3 s1, relu -----------------------
__global__ __launch_bounds__(256) void conv3_k(
    const float* __restrict__ in, const float* __restrict__ w,
    const float* __restrict__ bias, float* __restrict__ out) {
  int lane = threadIdx.x & 63;
  int wv = __builtin_amdgcn_readfirstlane(threadIdx.x >> 6);
  int oc0 = blockIdx.y * 32 + wv * 8;
  int p = blockIdx.x * 64 + lane;          // 65536 pixels
  int b = p >> 6, rem = p & 63;
  int oy = rem >> 3, ox = rem & 7;
  const float* ib = in + (long)b * 6400 + oy * 10 + ox;
  const float* wp = w + oc0 * 576;
  float acc[8];
  #pragma unroll
  for (int c = 0; c < 8; ++c) acc[c] = bias[oc0 + c];
  #pragma unroll 2
  for (int i = 0; i < 64; ++i)
    #pragma unroll
    for (int ky = 0; ky < 3; ++ky)
      #pragma unroll
      for (int kx = 0; kx < 3; ++kx) {
        float v = ib[i * 100 + ky * 10 + kx];
        int t = i * 9 + ky * 3 + kx;
        #pragma unroll
        for (int c = 0; c < 8; ++c)
          acc[c] = fmaf(v, wp[c * 576 + t], acc[c]);
      }
  float* ob = out + ((long)b * 64 + oc0) * 64 + rem;
  #pragma unroll
  for (int c = 0; c < 8; ++c) ob[c * 64] = fmaxf(acc[c], 0.f);
}

// ---- VQ: argmin over 512 codes, write quant = emb[idx], per-block loss ----
// Block b handles all 64 positions of image b. 8 rows x 8 codes register tile.
__global__ __launch_bounds__(256) void vq_k(
    const float* __restrict__ enc, const float* __restrict__ emb,
    float* __restrict__ quant, float* __restrict__ vqpart) {
  __shared__ float elT[64 * 516];    // e^T, padded: elT[d*516 + k]  (132 KB)
  __shared__ float qT[64 * 36];      // qT[d*36 + r], r<32 rows/pass (9 KB)
  __shared__ float qq_s[32];
  __shared__ float ee_s[512];
  __shared__ float lsum[4];

  int tid = threadIdx.x;
  int b = blockIdx.x;
  int lane = tid & 63;
  int w = tid >> 6;

  for (int s = tid; s < 512 * 64; s += 256) {
    int k = s >> 6, d = s & 63;
    elT[d * 516 + k] = emb[s];
  }
  __syncthreads();
  for (int kk = tid; kk < 512; kk += 256) {
    float s = 0.f;
    for (int d = 0; d < 64; ++d) { float e = elT[d * 516 + kk]; s = fmaf(e, e, s); }
    ee_s[kk] = s;
  }
  __syncthreads();
  float eer[8];
  #pragma unroll
  for (int j = 0; j < 2; ++j)
    #pragma unroll
    for (int c = 0; c < 4; ++c) eer[j * 4 + c] = ee_s[j * 256 + lane * 4 + c];

  float lossacc = 0.f;
  for (int pass = 0; pass < 2; ++pass) {
    int l0 = pass * 32;
    __syncthreads();
    for (int s = tid; s < 2048; s += 256) {
      int r = s & 31, d = s >> 5;
      qT[d * 36 + r] = enc[((b * 64 + d) << 6) + l0 + r];
    }
    __syncthreads();
    if (tid < 32) {
      float s = 0.f;
      for (int d = 0; d < 64; ++d) { float v = qT[d * 36 + tid]; s = fmaf(v, v, s); }
      qq_s[tid] = s;
    }
    __syncthreads();

    int r0 = w * 8;
    float dot[8][8] = {};
    #pragma unroll 2
    for (int d = 0; d < 64; ++d) {
      float4 e0 = *(const float4*)&elT[d * 516 + lane * 4];
      float4 e1 = *(const float4*)&elT[d * 516 + 256 + lane * 4];
      float4 q0 = *(const float4*)&qT[d * 36 + r0];
      float4 q1 = *(const float4*)&qT[d * 36 + r0 + 4];
      float qv[8] = {q0.x, q0.y, q0.z, q0.w, q1.x, q1.y, q1.z, q1.w};
      float ev[8] = {e0.x, e0.y, e0.z, e0.w, e1.x, e1.y, e1.z, e1.w};
      #pragma unroll
      for (int r = 0; r < 8; ++r)
        #pragma unroll
        for (int je = 0; je < 8; ++je)
          dot[r][je] = fmaf(qv[r], ev[je], dot[r][je]);
    }

    #pragma unroll 1
    for (int r = 0; r < 8; ++r) {
      float best = 1e30f; int bk = 0;
      #pragma unroll
      for (int je = 0; je < 8; ++je) {
        float sc = fmaf(-2.f, dot[r][je], eer[je]);
        int k = (je >> 2) * 256 + lane * 4 + (je & 3);
        if (sc < best || (sc == best && k < bk)) { best = sc; bk = k; }
      }
      #pragma unroll
      for (int off = 32; off; off >>= 1) {
        float ob = __shfl_xor(best, off);
        int ok = __shfl_xor(bk, off);
        if (ob < best || (ob == best && ok < bk)) { best = ob; bk = ok; }
      }
      int l = l0 + r0 + r;
      quant[((b << 6) + lane) * 64 + l] = emb[bk * 64 + lane];
      if (lane == 0) lossacc += qq_s[r0 + r] + best;
    }
  }
  if (lane == 0) lsum[w] = lossacc;
  __syncthreads();
  if (tid == 0) vqpart[b] = lsum[0] + lsum[1] + lsum[2] + lsum[3];
}

// ---- deconv1: [B,64,8,8] -> [B,64,10,10], k3 s1 pad2(full), relu ----------
__global__ __launch_bounds__(256) void dec1_k(
    const float* __restrict__ in, const float* __restrict__ w,
    const float* __restrict__ bias, float* __restrict__ out) {
  int lane = threadIdx.x & 63;
  int wv = __builtin_amdgcn_readfirstlane(threadIdx.x >> 6);
  int oc0 = blockIdx.y * 32 + wv * 8;
  int p = blockIdx.x * 64 + lane;          // 102400 pixels
  int b = p / 100, rem = p % 100;
  int oy = rem / 10, ox = rem % 10;
  const float* ib = in + (long)b * 4096;
  const float* wp = w + oc0 * 576;
  float acc[8];
  #pragma unroll
  for (int cc = 0; cc < 8; ++cc) acc[cc] = bias[oc0 + cc];
  for (int ky = 0; ky < 3; ++ky) {
    int iy = oy + ky - 2;
    if ((unsigned)iy >= 8u) continue;
    for (int kx = 0; kx < 3; ++kx) {
      int ix = ox + kx - 2;
      if ((unsigned)ix >= 8u) continue;
      const float* wt = wp + ky * 3 + kx;
      const float* ibt = ib + iy * 8 + ix;
      #pragma unroll 2
      for (int i = 0; i < 64; ++i) {
        float v = ibt[i * 64];
        #pragma unroll
        for (int cc = 0; cc < 8; ++cc)
          acc[cc] = fmaf(v, wt[cc * 576 + i * 9], acc[cc]);
      }
    }
  }
  float* ob = out + ((long)b * 64 + oc0) * 100 + rem;
  #pragma unroll
  for (int cc = 0; cc < 8; ++cc) ob[cc * 100] = fmaxf(acc[cc], 0.f);
}

// ---- deconv2: [B,64,10,10] -> [B,32,21,21], k3 s2, relu; 4 parity classes -
__global__ __launch_bounds__(256) void dec2_k(
    const float* __restrict__ in, const float* __restrict__ w,
    const float* __restrict__ bias, float* __restrict__ out) {
  int lane = threadIdx.x & 63;
  int wv = __builtin_amdgcn_readfirstlane(threadIdx.x >> 6);
  int oc0 = wv * 8;                        // 32 oc
  int cls = blockIdx.y;                    // parity class
  int a = cls >> 1, c = cls & 1;
  int U = a ? 10 : 11, V = c ? 10 : 11;
  int b = blockIdx.x >> 1;
  int p = (blockIdx.x & 1) * 64 + lane;
  if (p >= U * V) return;
  int u = p / V, v = p % V;
  int oy = 2 * u + a, ox = 2 * v + c;
  int ny = a ? 1 : 2, nx = c ? 1 : 2;
  int iyb = a ? u : u - 1, ixb = c ? v : v - 1;
  int kyb = a ? 1 : 0, kxb = c ? 1 : 0;
  const float* ib = in + (long)b * 6400;
  const float* wp = w + oc0 * 576;
  float acc[8];
  #pragma unroll
  for (int cc = 0; cc < 8; ++cc) acc[cc] = bias[oc0 + cc];
  for (int ty = 0; ty < ny; ++ty) {
    int iy = iyb + ty;
    if ((unsigned)iy >= 10u) continue;
    int ky = kyb + 2 * ty;
    for (int tx = 0; tx < nx; ++tx) {
      int ix = ixb + tx;
      if ((unsigned)ix >= 10u) continue;
      int kx = kxb + 2 * tx;
      const float* wt = wp + ky * 3 + kx;
      const float* ibt = ib + iy * 10 + ix;
      #pragma unroll 2
      for (int i = 0; i < 64; ++i) {
        float vv = ibt[i * 100];
        #pragma unroll
        for (int cc = 0; cc < 8; ++cc)
          acc[cc] = fmaf(vv, wt[cc * 576 + i * 9], acc[cc]);
      }
    }
  }
  float* ob = out + ((long)b * 32 + oc0) * 441 + oy * 21 + ox;
  #pragma unroll
  for (int cc = 0; cc < 8; ++cc) ob[cc * 441] = fmaxf(acc[cc], 0.f);
}

// ---- deconv3 + sigmoid + rec-loss, 4x4 tile/thread, NO atomics ------------
// Aligned 4x4 output tile (y0=4ty, x0=4tx) depends on exactly one d2 pixel
// (ty,tx): ky=3-ry, kx=3-rx, iy=ty, ix=tx. One thread = one tile, all 32 ch.
__global__ __launch_bounds__(256) void dec3_k(
    const float* __restrict__ d2, const float* __restrict__ dw3,
    const float* __restrict__ db3, const float* __restrict__ x,
    float* __restrict__ part) {
  int t = blockIdx.x * 256 + threadIdx.x;      // 451584 tiles = 1764 blocks
  int b = t / 441, r = t % 441;
  int ty = r / 21, tx = r % 21;
  const float* ib = d2 + (long)b * 14112 + ty * 21 + tx;
  float acc[4][4][4];                          // [c][ry][rx]
  #pragma unroll
  for (int c = 0; c < 4; ++c) {
    float bv = db3[c];
    #pragma unroll
    for (int ry = 0; ry < 4; ++ry)
      #pragma unroll
      for (int rx = 0; rx < 4; ++rx) acc[c][ry][rx] = bv;
  }
  #pragma unroll 4
  for (int i = 0; i < 32; ++i) {
    float v = ib[i * 441];
    #pragma unroll
    for (int c = 0; c < 4; ++c) {
      const float* wp = dw3 + (c * 32 + i) * 16;
      #pragma unroll
      for (int ky = 0; ky < 4; ++ky) {
        float4 wv = *(const float4*)(wp + ky * 4);
        int ry = 3 - ky;                       // kx=0..3 -> rx=3..0
        acc[c][ry][3] = fmaf(v, wv.x, acc[c][ry][3]);
        acc[c][ry][2] = fmaf(v, wv.y, acc[c][ry][2]);
        acc[c][ry][1] = fmaf(v, wv.z, acc[c][ry][1]);
        acc[c][ry][0] = fmaf(v, wv.w, acc[c][ry][0]);
      }
    }
  }
  int y0 = ty * 4, x0 = tx * 4;
  const float* xb = x + (long)b * 28224 + y0 * 84 + x0;
  float ls = 0.f;
  #pragma unroll
  for (int c = 0; c < 4; ++c)
    #pragma unroll
    for (int ry = 0; ry < 4; ++ry) {
      float4 xv = *(const float4*)(xb + c * 7056 + ry * 84);
      float xs[4] = {xv.x, xv.y, xv.z, xv.w};
      #pragma unroll
      for (int rx = 0; rx < 4; ++rx) {
        float dec = 1.f / (1.f + __expf(-acc[c][ry][rx]));
        float df = dec - xs[rx] * (1.f / 255.f);
        ls = fmaf(df, df, ls);
      }
    }
  #pragma unroll
  for (int off = 32; off; off >>= 1) ls += __shfl_down(ls, off);
  __shared__ float r4[4];
  if ((threadIdx.x & 63) == 0) r4[threadIdx.x >> 6] = ls;
  __syncthreads();
  if (threadIdx.x == 0) part[blockIdx.x] = r4[0] + r4[1] + r4[2] + r4[3];
}

// ---- reduce: sum dec3 partials (1764) and vq partials (1024) into accum ---
__global__ __launch_bounds__(256) void reduce_k(
    const float* __restrict__ dec3part, const float* __restrict__ vqpart,
    float* __restrict__ accum) {
  int tid = threadIdx.x;
  float s0 = 0.f, s1 = 0.f;
  for (int i = tid; i < 1764; i += 256) s0 += dec3part[i];
  for (int i = tid; i < 1024; i += 256) s1 += vqpart[i];
  #pragma unroll
  for (int off = 32; off; off >>= 1) {
    s0 += __shfl_down(s0, off);
    s1 += __shfl_down(s1, off);
  }
  __shared__ float a0[4], a1[4];
  int lane = tid & 63, w = tid >> 6;
  if (lane == 0) { a0[w] = s0; a1[w] = s1; }
  __syncthreads();
  if (tid == 0) {
    accum[0] = a0[0] + a0[1] + a0[2] + a0[3];
    accum[1] = a1[0] + a1[1] + a1[2] + a1[3];
  }
}

// ---- FC1: hidden += quant_flat @ lw1 (k-split 4, 16-batch regs, atomics) --
__global__ __launch_bounds__(256) void fc1_k(
    const float* __restrict__ quant, const float* __restrict__ lw1,
    float* __restrict__ hidden) {
  int n = (blockIdx.x & 1) * 256 + threadIdx.x;
  int bg = (blockIdx.x >> 1) & 63;
  int ks = blockIdx.x >> 7;                // 0..3
  int b0 = bg * 16;
  const float* q0 = quant + (long)b0 * 4096 + ks * 1024;
  const float* w0 = lw1 + (long)ks * 1024 * 512 + n;
  float acc[16] = {};
  #pragma unroll 4
  for (int k = 0; k < 1024; ++k) {
    float wvv = w0[(long)k * 512];
    #pragma unroll
    for (int bb = 0; bb < 16; ++bb)
      acc[bb] = fmaf(q0[bb * 4096 + k], wvv, acc[bb]);
  }
  #pragma unroll
  for (int bb = 0; bb < 16; ++bb)
    atomicAdd(&hidden[(b0 + bb) * 512 + n], acc[bb]);
}

// ---- FC2: q_values = relu(hidden + lb1) @ lw2 + lb2; write losses ---------
__global__ __launch_bounds__(256) void fc2_k(
    const float* __restrict__ hidden, const float* __restrict__ lb1,
    const float* __restrict__ lw2, const float* __restrict__ lb2,
    const float* __restrict__ accum, float* __restrict__ out) {
  int t = blockIdx.x * 256 + threadIdx.x;  // 18432
  int b = t / 18, a = t % 18;
  const float* h = hidden + b * 512;
  float acc = lb2[a];
  #pragma unroll 4
  for (int n = 0; n < 512; ++n) {
    float hv = fmaxf(h[n] + lb1[n], 0.f);
    acc = fmaf(hv, lw2[n * 18 + a], acc);
  }
  out[t] = acc;
  if (t == 0) {
    out[18432] = accum[0] * (1.f / 28901376.f);          // /(1024*4*84*84)
    out[18433] = 1.25f * accum[1] * (1.f / 4194304.f);   // /(65536*64)
  }
}

extern "C" void kernel_launch(void* const* d_in, const int* in_sizes, int n_in,
                              void* d_out, int out_size, void* d_ws, size_t ws_size,
                              hipStream_t stream) {
  const float* x   = (const float*)d_in[0];
  const float* w1  = (const float*)d_in[1];
  const float* b1  = (const float*)d_in[2];
  const float* w2  = (const float*)d_in[3];
  const float* b2  = (const float*)d_in[4];
  const float* w3  = (const float*)d_in[5];
  const float* b3  = (const float*)d_in[6];
  const float* emb = (const float*)d_in[7];
  const float* dw1 = (const float*)d_in[8];
  const float* db1 = (const float*)d_in[9];
  const float* dw2 = (const float*)d_in[10];
  const float* db2 = (const float*)d_in[11];
  const float* dw3 = (const float*)d_in[12];
  const float* db3 = (const float*)d_in[13];
  const float* lw1 = (const float*)d_in[14];
  const float* lb1 = (const float*)d_in[15];
  const float* lw2 = (const float*)d_in[16];
  const float* lb2 = (const float*)d_in[17];

  float* ws = (float*)d_ws;
  float* h1     = ws;                    // 14450688 floats [B,32,21,21]
  float* h2     = ws + 14450688;         //  6553600 floats [B,64,10,10]
  float* enc    = ws + 21004288;         //  4194304 floats [B,64,8,8]
  float* quant  = ws + 25198592;         //  4194304 floats [B,64,8,8]
  float* d1     = h2;                    // reuse (h2 dead after conv3)
  float* d2b    = h1;                    // reuse (h1 dead after conv2)
  float* hidden = ws + 29392896;         //   524288 floats [B,512]
  float* accum  = ws + 29917184;         // [0]=rec sum, [1]=quant sum
  float* d3part = ws + 29917192;         // 1764 floats
  float* vqpart = ws + 29918956;         // 1024 floats
  float* outp   = (float*)d_out;

  zero_k<<<2048, 256, 0, stream>>>(hidden, accum);
  conv1_k<<<dim3(7056, 1), 256, 0, stream>>>(x, w1, b1, h1);
  conv2_k<<<dim3(1600, 2), 256, 0, stream>>>(h1, w2, b2, h2);
  conv3_k<<<dim3(1024, 2), 256, 0, stream>>>(h2, w3, b3, enc);
  vq_k<<<1024, 256, 0, stream>>>(enc, emb, quant, vqpart);
  dec1_k<<<dim3(1600, 2), 256, 0, stream>>>(quant, dw1, db1, d1);
  dec2_k<<<dim3(2048, 4), 256, 0, stream>>>(d1, dw2, db2, d2b);
  dec3_k<<<1764, 256, 0, stream>>>(d2b, dw3, db3, x, d3part);
  reduce_k<<<1, 256, 0, stream>>>(d3part, vqpart, accum);
  fc1_k<<<512, 256, 0, stream>>>(quant, lw1, hidden);
  fc2_k<<<72, 256, 0, stream>>>(hidden, lb1, lw2, lb2, accum, outp);
}

// Round 4
// 1221.694 us; speedup vs baseline: 1.4304x; 1.1549x over previous
//
#include <hip/hip_runtime.h>
#include <hip/hip_bf16.h>

// ---------------------------------------------------------------------------
// VQ-VAE QNetwork forward, fp32 throughout (VQ argmin must match np fp32).
// Layouts all NCHW-flat. B=1024.
//   h1  [B,32,21,21]   h2 [B,64,10,10]  enc [B,64,8,8]  quant [B,64,8,8]
//   d1  [B,64,10,10]   d2 [B,32,21,21]  hidden [B,512]
// Conv family: block = one image, input staged in LDS, wave = 16 (or 8) oc,
// lane = output pixel; weights wave-uniform (scalar loads).
// ---------------------------------------------------------------------------

#define ENC_SCALE (1.0f/65025.0f)   // (x/255)/255

__global__ __launch_bounds__(256) void zero_k(float* __restrict__ hidden,
                                              float* __restrict__ accum) {
  int t = blockIdx.x * 256 + threadIdx.x;
  if (t < 524288) hidden[t] = 0.f;
  if (t < 8) accum[t] = 0.f;
}

// ---- conv1: [B,4,84,84] -> [B,32,21,21], k4 s4, scale 1/255^2, relu -------
__global__ __launch_bounds__(256) void conv1_k(
    const float* __restrict__ x, const float* __restrict__ w1,
    const float* __restrict__ b1, float* __restrict__ out) {
  int lane = threadIdx.x & 63;
  int wv = __builtin_amdgcn_readfirstlane(threadIdx.x >> 6);
  int oc0 = wv * 8;                        // 4 waves -> 32 oc
  int p = blockIdx.x * 64 + lane;          // 451584 pixels
  int b = p / 441, rem = p % 441;
  int oy = rem / 21, ox = rem % 21;
  const float* xb = x + (long)b * 28224 + (oy * 4) * 84 + ox * 4;
  const float* wp = w1 + oc0 * 64;
  float acc[8];
  #pragma unroll
  for (int c = 0; c < 8; ++c) acc[c] = b1[oc0 + c];
  #pragma unroll 1
  for (int i = 0; i < 4; ++i)
    #pragma unroll
    for (int ky = 0; ky < 4; ++ky)
      #pragma unroll
      for (int kx = 0; kx < 4; ++kx) {
        float v = xb[i * 7056 + ky * 84 + kx] * ENC_SCALE;
        int t = i * 16 + ky * 4 + kx;
        #pragma unroll
        for (int c = 0; c < 8; ++c)
          acc[c] = fmaf(v, wp[c * 64 + t], acc[c]);
      }
  float* ob = out + ((long)b * 32 + oc0) * 441 + rem;
  #pragma unroll
  for (int c = 0; c < 8; ++c) ob[c * 441] = fmaxf(acc[c], 0.f);
}

// ---- conv2: [B,32,21,21] -> [B,64,10,10], k3 s2, relu. Block = image. -----
__global__ __launch_bounds__(256) void conv2_k(
    const float* __restrict__ in, const float* __restrict__ w,
    const float* __restrict__ bias, float* __restrict__ out) {
  __shared__ float in_s[32 * 441];         // 56.4 KB
  int b = blockIdx.x, tid = threadIdx.x;
  const float4* src = (const float4*)(in + (long)b * 14112);
  for (int i = tid; i < 3528; i += 256) *(float4*)&in_s[i * 4] = src[i];
  __syncthreads();
  int lane = tid & 63;
  int wv = __builtin_amdgcn_readfirstlane(tid >> 6);
  int oc0 = wv * 16;
  int pxA = lane;                          // 0..63
  int pxB = 64 + lane; if (pxB > 99) pxB = 99;
  int oyA = pxA / 10, oxA = pxA % 10;
  int oyB = pxB / 10, oxB = pxB % 10;
  float accA[16], accB[16];
  #pragma unroll
  for (int o = 0; o < 16; ++o) { float bv = bias[oc0 + o]; accA[o] = bv; accB[o] = bv; }
  #pragma unroll 2
  for (int ic = 0; ic < 32; ++ic) {
    const float* is = in_s + ic * 441;
    float a[9], bb[9];
    #pragma unroll
    for (int ky = 0; ky < 3; ++ky)
      #pragma unroll
      for (int kx = 0; kx < 3; ++kx) {
        a[ky * 3 + kx]  = is[(2 * oyA + ky) * 21 + 2 * oxA + kx];
        bb[ky * 3 + kx] = is[(2 * oyB + ky) * 21 + 2 * oxB + kx];
      }
    #pragma unroll
    for (int o = 0; o < 16; ++o) {
      const float* wp = w + (long)(oc0 + o) * 288 + ic * 9;
      #pragma unroll
      for (int t = 0; t < 9; ++t) {
        float wt = wp[t];
        accA[o] = fmaf(a[t], wt, accA[o]);
        accB[o] = fmaf(bb[t], wt, accB[o]);
      }
    }
  }
  float* ob = out + ((long)b * 64 + oc0) * 100;
  #pragma unroll
  for (int o = 0; o < 16; ++o) {
    ob[o * 100 + pxA] = fmaxf(accA[o], 0.f);
    if (lane < 36) ob[o * 100 + 64 + lane] = fmaxf(accB[o], 0.f);
  }
}

// ---- conv3: [B,64,10,10] -> [B,64,8,8], k3 s1, relu. Block = image. -------
__global__ __launch_bounds__(256) void conv3_k(
    const float* __restrict__ in, const float* __restrict__ w,
    const float* __restrict__ bias, float* __restrict__ out) {
  __shared__ float in_s[6400];             // 25.6 KB
  int b = blockIdx.x, tid = threadIdx.x;
  const float4* src = (const float4*)(in + (long)b * 6400);
  for (int i = tid; i < 1600; i += 256) *(float4*)&in_s[i * 4] = src[i];
  __syncthreads();
  int lane = tid & 63;
  int wv = __builtin_amdgcn_readfirstlane(tid >> 6);
  int oc0 = wv * 16;
  int oy = lane >> 3, ox = lane & 7;       // 64 px exactly
  float acc[16];
  #pragma unroll
  for (int o = 0; o < 16; ++o) acc[o] = bias[oc0 + o];
  #pragma unroll 2
  for (int ic = 0; ic < 64; ++ic) {
    const float* is = in_s + ic * 100;
    float a[9];
    #pragma unroll
    for (int ky = 0; ky < 3; ++ky)
      #pragma unroll
      for (int kx = 0; kx < 3; ++kx)
        a[ky * 3 + kx] = is[(oy + ky) * 10 + ox + kx];
    #pragma unroll
    for (int o = 0; o < 16; ++o) {
      const float* wp = w + (long)(oc0 + o) * 576 + ic * 9;
      #pragma unroll
      for (int t = 0; t < 9; ++t) acc[o] = fmaf(a[t], wp[t], acc[o]);
    }
  }
  float* ob = out + ((long)b * 64 + oc0) * 64 + lane;
  #pragma unroll
  for (int o = 0; o < 16; ++o) ob[o * 64] = fmaxf(acc[o], 0.f);
}

// ---- VQ: argmin over 512 codes, write quant = emb[idx], per-block loss ----
__global__ __launch_bounds__(256) void vq_k(
    const float* __restrict__ enc, const float* __restrict__ emb,
    float* __restrict__ quant, float* __restrict__ vqpart) {
  __shared__ float elT[64 * 516];    // e^T, padded: elT[d*516 + k]  (132 KB)
  __shared__ float qT[64 * 36];      // qT[d*36 + r], r<32 rows/pass (9 KB)
  __shared__ float qq_s[32];
  __shared__ float ee_s[512];
  __shared__ float lsum[4];

  int tid = threadIdx.x;
  int b = blockIdx.x;
  int lane = tid & 63;
  int w = tid >> 6;

  for (int s = tid; s < 512 * 64; s += 256) {
    int k = s >> 6, d = s & 63;
    elT[d * 516 + k] = emb[s];
  }
  __syncthreads();
  for (int kk = tid; kk < 512; kk += 256) {
    float s = 0.f;
    for (int d = 0; d < 64; ++d) { float e = elT[d * 516 + kk]; s = fmaf(e, e, s); }
    ee_s[kk] = s;
  }
  __syncthreads();
  float eer[8];
  #pragma unroll
  for (int j = 0; j < 2; ++j)
    #pragma unroll
    for (int c = 0; c < 4; ++c) eer[j * 4 + c] = ee_s[j * 256 + lane * 4 + c];

  float lossacc = 0.f;
  for (int pass = 0; pass < 2; ++pass) {
    int l0 = pass * 32;
    __syncthreads();
    for (int s = tid; s < 2048; s += 256) {
      int r = s & 31, d = s >> 5;
      qT[d * 36 + r] = enc[((b * 64 + d) << 6) + l0 + r];
    }
    __syncthreads();
    if (tid < 32) {
      float s = 0.f;
      for (int d = 0; d < 64; ++d) { float v = qT[d * 36 + tid]; s = fmaf(v, v, s); }
      qq_s[tid] = s;
    }
    __syncthreads();

    int r0 = w * 8;
    float dot[8][8] = {};
    #pragma unroll 2
    for (int d = 0; d < 64; ++d) {
      float4 e0 = *(const float4*)&elT[d * 516 + lane * 4];
      float4 e1 = *(const float4*)&elT[d * 516 + 256 + lane * 4];
      float4 q0 = *(const float4*)&qT[d * 36 + r0];
      float4 q1 = *(const float4*)&qT[d * 36 + r0 + 4];
      float qv[8] = {q0.x, q0.y, q0.z, q0.w, q1.x, q1.y, q1.z, q1.w};
      float ev[8] = {e0.x, e0.y, e0.z, e0.w, e1.x, e1.y, e1.z, e1.w};
      #pragma unroll
      for (int r = 0; r < 8; ++r)
        #pragma unroll
        for (int je = 0; je < 8; ++je)
          dot[r][je] = fmaf(qv[r], ev[je], dot[r][je]);
    }

    #pragma unroll 1
    for (int r = 0; r < 8; ++r) {
      float best = 1e30f; int bk = 0;
      #pragma unroll
      for (int je = 0; je < 8; ++je) {
        float sc = fmaf(-2.f, dot[r][je], eer[je]);
        int k = (je >> 2) * 256 + lane * 4 + (je & 3);
        if (sc < best || (sc == best && k < bk)) { best = sc; bk = k; }
      }
      #pragma unroll
      for (int off = 32; off; off >>= 1) {
        float ob = __shfl_xor(best, off);
        int ok = __shfl_xor(bk, off);
        if (ob < best || (ob == best && ok < bk)) { best = ob; bk = ok; }
      }
      int l = l0 + r0 + r;
      quant[((b << 6) + lane) * 64 + l] = emb[bk * 64 + lane];
      if (lane == 0) lossacc += qq_s[r0 + r] + best;
    }
  }
  if (lane == 0) lsum[w] = lossacc;
  __syncthreads();
  if (tid == 0) vqpart[b] = lsum[0] + lsum[1] + lsum[2] + lsum[3];
}

// ---- deconv1: [B,64,8,8] -> [B,64,10,10], full-corr k3. Block = image. ----
// Padded LDS plane 12x12 per ic: data at rows/cols 2..9, zeros elsewhere.
// out(oy,ox) += in[iy=oy+ky-2][ix=ox+kx-2]*w[oc][ic][ky][kx] -> padded row oy+ky.
__global__ __launch_bounds__(256) void dec1_k(
    const float* __restrict__ in, const float* __restrict__ w,
    const float* __restrict__ bias, float* __restrict__ out) {
  __shared__ float in_s[64 * 144];         // 36.9 KB
  int b = blockIdx.x, tid = threadIdx.x;
  for (int i = tid; i < 9216; i += 256) in_s[i] = 0.f;
  __syncthreads();
  const float* src = in + (long)b * 4096;
  for (int i = tid; i < 4096; i += 256) {
    int ic = i >> 6, p = i & 63;
    in_s[ic * 144 + (2 + (p >> 3)) * 12 + 2 + (p & 7)] = src[i];
  }
  __syncthreads();
  int lane = tid & 63;
  int wv = __builtin_amdgcn_readfirstlane(tid >> 6);
  int oc0 = wv * 16;
  int pxA = lane;
  int pxB = 64 + lane; if (pxB > 99) pxB = 99;
  int oyA = pxA / 10, oxA = pxA % 10;
  int oyB = pxB / 10, oxB = pxB % 10;
  float accA[16], accB[16];
  #pragma unroll
  for (int o = 0; o < 16; ++o) { float bv = bias[oc0 + o]; accA[o] = bv; accB[o] = bv; }
  #pragma unroll 2
  for (int ic = 0; ic < 64; ++ic) {
    const float* is = in_s + ic * 144;
    float a[9], bb[9];
    #pragma unroll
    for (int ky = 0; ky < 3; ++ky)
      #pragma unroll
      for (int kx = 0; kx < 3; ++kx) {
        a[ky * 3 + kx]  = is[(oyA + ky) * 12 + oxA + kx];
        bb[ky * 3 + kx] = is[(oyB + ky) * 12 + oxB + kx];
      }
    #pragma unroll
    for (int o = 0; o < 16; ++o) {
      const float* wp = w + (long)(oc0 + o) * 576 + ic * 9;
      #pragma unroll
      for (int t = 0; t < 9; ++t) {
        float wt = wp[t];
        accA[o] = fmaf(a[t], wt, accA[o]);
        accB[o] = fmaf(bb[t], wt, accB[o]);
      }
    }
  }
  float* ob = out + ((long)b * 64 + oc0) * 100;
  #pragma unroll
  for (int o = 0; o < 16; ++o) {
    ob[o * 100 + pxA] = fmaxf(accA[o], 0.f);
    if (lane < 36) ob[o * 100 + 64 + lane] = fmaxf(accB[o], 0.f);
  }
}

// ---- deconv2: [B,64,10,10] -> [B,32,21,21], k3 s2, relu. Block = image. ---
// Padded LDS 12x12 per ic (rows/cols 0..9 data, 10..11 zero).
// iy=(oy-ky+2)/2 valid when (oy+ky) even. Parity-uniform passes.
__global__ __launch_bounds__(256) void dec2_k(
    const float* __restrict__ in, const float* __restrict__ w,
    const float* __restrict__ bias, float* __restrict__ out) {
  __shared__ float in_s[64 * 144];         // 36.9 KB
  int b = blockIdx.x, tid = threadIdx.x;
  for (int i = tid; i < 9216; i += 256) in_s[i] = 0.f;
  __syncthreads();
  const float* src = in + (long)b * 6400;
  for (int i = tid; i < 6400; i += 256) {
    int ic = i / 100, p = i % 100;
    in_s[ic * 144 + (p / 10) * 12 + (p % 10)] = src[i];
  }
  __syncthreads();
  int lane = tid & 63;
  int wv = __builtin_amdgcn_readfirstlane(tid >> 6);
  int oc0 = wv * 8;
  float* ob = out + ((long)b * 32 + oc0) * 441;
  float bias8[8];
  #pragma unroll
  for (int o = 0; o < 8; ++o) bias8[o] = bias[oc0 + o];

  // class0: oy=2u, ox=2v (11x11=121). taps (w-idx,row,col): (0,u+1,v+1)(2,u+1,v)(6,u,v+1)(8,u,v)
  #pragma unroll 1
  for (int pp = 0; pp < 2; ++pp) {
    int idx = pp * 64 + lane; bool okl = idx < 121; int ii = okl ? idx : 0;
    int u = ii / 11, v = ii % 11;
    float acc[8];
    #pragma unroll
    for (int o = 0; o < 8; ++o) acc[o] = bias8[o];
    #pragma unroll 2
    for (int ic = 0; ic < 64; ++ic) {
      const float* is = in_s + ic * 144;
      float i00 = is[(u + 1) * 12 + v + 1];
      float i02 = is[(u + 1) * 12 + v];
      float i20 = is[u * 12 + v + 1];
      float i22 = is[u * 12 + v];
      #pragma unroll
      for (int o = 0; o < 8; ++o) {
        const float* wp = w + (long)(oc0 + o) * 576 + ic * 9;
        acc[o] = fmaf(i00, wp[0], acc[o]);
        acc[o] = fmaf(i02, wp[2], acc[o]);
        acc[o] = fmaf(i20, wp[6], acc[o]);
        acc[o] = fmaf(i22, wp[8], acc[o]);
      }
    }
    if (okl) {
      int off = (2 * u) * 21 + 2 * v;
      #pragma unroll
      for (int o = 0; o < 8; ++o) ob[o * 441 + off] = fmaxf(acc[o], 0.f);
    }
  }
  // class1: oy=2u, ox=2v+1 (11x10=110). kx=1 -> ix=v+1. taps: (1,u+1,v+1)(7,u,v+1)
  #pragma unroll 1
  for (int pp = 0; pp < 2; ++pp) {
    int idx = pp * 64 + lane; bool okl = idx < 110; int ii = okl ? idx : 0;
    int u = ii / 10, v = ii % 10;
    float acc[8];
    #pragma unroll
    for (int o = 0; o < 8; ++o) acc[o] = bias8[o];
    #pragma unroll 2
    for (int ic = 0; ic < 64; ++ic) {
      const float* is = in_s + ic * 144;
      float i0 = is[(u + 1) * 12 + v + 1];
      float i2 = is[u * 12 + v + 1];
      #pragma unroll
      for (int o = 0; o < 8; ++o) {
        const float* wp = w + (long)(oc0 + o) * 576 + ic * 9;
        acc[o] = fmaf(i0, wp[1], acc[o]);
        acc[o] = fmaf(i2, wp[7], acc[o]);
      }
    }
    if (okl) {
      int off = (2 * u) * 21 + 2 * v + 1;
      #pragma unroll
      for (int o = 0; o < 8; ++o) ob[o * 441 + off] = fmaxf(acc[o], 0.f);
    }
  }
  // class2: oy=2u+1, ox=2v (10x11=110). ky=1 -> iy=u+1. taps: (3,u+1,v+1)(5,u+1,v)
  #pragma unroll 1
  for (int pp = 0; pp < 2; ++pp) {
    int idx = pp * 64 + lane; bool okl = idx < 110; int ii = okl ? idx : 0;
    int u = ii / 11, v = ii % 11;
    float acc[8];
    #pragma unroll
    for (int o = 0; o < 8; ++o) acc[o] = bias8[o];
    #pragma unroll 2
    for (int ic = 0; ic < 64; ++ic) {
      const float* is = in_s + ic * 144;
      float i0 = is[(u + 1) * 12 + v + 1];
      float i2 = is[(u + 1) * 12 + v];
      #pragma unroll
      for (int o = 0; o < 8; ++o) {
        const float* wp = w + (long)(oc0 + o) * 576 + ic * 9;
        acc[o] = fmaf(i0, wp[3], acc[o]);
        acc[o] = fmaf(i2, wp[5], acc[o]);
      }
    }
    if (okl) {
      int off = (2 * u + 1) * 21 + 2 * v;
      #pragma unroll
      for (int o = 0; o < 8; ++o) ob[o * 441 + off] = fmaxf(acc[o], 0.f);
    }
  }
  // class3: oy=2u+1, ox=2v+1 (10x10=100). tap: (4,u+1,v+1)
  #pragma unroll 1
  for (int pp = 0; pp < 2; ++pp) {
    int idx = pp * 64 + lane; bool okl = idx < 100; int ii = okl ? idx : 0;
    int u = ii / 10, v = ii % 10;
    float acc[8];
    #pragma unroll
    for (int o = 0; o < 8; ++o) acc[o] = bias8[o];
    #pragma unroll 2
    for (int ic = 0; ic < 64; ++ic) {
      const float* is = in_s + ic * 144;
      float i0 = is[(u + 1) * 12 + v + 1];
      #pragma unroll
      for (int o = 0; o < 8; ++o) {
        const float* wp = w + (long)(oc0 + o) * 576 + ic * 9;
        acc[o] = fmaf(i0, wp[4], acc[o]);
      }
    }
    if (okl) {
      int off = (2 * u + 1) * 21 + 2 * v + 1;
      #pragma unroll
      for (int o = 0; o < 8; ++o) ob[o * 441 + off] = fmaxf(acc[o], 0.f);
    }
  }
}

// ---- deconv3 + sigmoid + rec-loss, 4x4 tile/thread, NO atomics ------------
__global__ __launch_bounds__(256) void dec3_k(
    const float* __restrict__ d2, const float* __restrict__ dw3,
    const float* __restrict__ db3, const float* __restrict__ x,
    float* __restrict__ part) {
  int t = blockIdx.x * 256 + threadIdx.x;      // 451584 tiles = 1764 blocks
  int b = t / 441, r = t % 441;
  int ty = r / 21, tx = r % 21;
  const float* ib = d2 + (long)b * 14112 + ty * 21 + tx;
  float acc[4][4][4];                          // [c][ry][rx]
  #pragma unroll
  for (int c = 0; c < 4; ++c) {
    float bv = db3[c];
    #pragma unroll
    for (int ry = 0; ry < 4; ++ry)
      #pragma unroll
      for (int rx = 0; rx < 4; ++rx) acc[c][ry][rx] = bv;
  }
  #pragma unroll 4
  for (int i = 0; i < 32; ++i) {
    float v = ib[i * 441];
    #pragma unroll
    for (int c = 0; c < 4; ++c) {
      const float* wp = dw3 + (c * 32 + i) * 16;
      #pragma unroll
      for (int ky = 0; ky < 4; ++ky) {
        float4 wv = *(const float4*)(wp + ky * 4);
        int ry = 3 - ky;
        acc[c][ry][3] = fmaf(v, wv.x, acc[c][ry][3]);
        acc[c][ry][2] = fmaf(v, wv.y, acc[c][ry][2]);
        acc[c][ry][1] = fmaf(v, wv.z, acc[c][ry][1]);
        acc[c][ry][0] = fmaf(v, wv.w, acc[c][ry][0]);
      }
    }
  }
  int y0 = ty * 4, x0 = tx * 4;
  const float* xb = x + (long)b * 28224 + y0 * 84 + x0;
  float ls = 0.f;
  #pragma unroll
  for (int c = 0; c < 4; ++c)
    #pragma unroll
    for (int ry = 0; ry < 4; ++ry) {
      float4 xv = *(const float4*)(xb + c * 7056 + ry * 84);
      float xs[4] = {xv.x, xv.y, xv.z, xv.w};
      #pragma unroll
      for (int rx = 0; rx < 4; ++rx) {
        float dec = 1.f / (1.f + __expf(-acc[c][ry][rx]));
        float df = dec - xs[rx] * (1.f / 255.f);
        ls = fmaf(df, df, ls);
      }
    }
  #pragma unroll
  for (int off = 32; off; off >>= 1) ls += __shfl_down(ls, off);
  __shared__ float r4[4];
  if ((threadIdx.x & 63) == 0) r4[threadIdx.x >> 6] = ls;
  __syncthreads();
  if (threadIdx.x == 0) part[blockIdx.x] = r4[0] + r4[1] + r4[2] + r4[3];
}

// ---- reduce: sum dec3 partials (1764) and vq partials (1024) into accum ---
__global__ __launch_bounds__(256) void reduce_k(
    const float* __restrict__ dec3part, const float* __restrict__ vqpart,
    float* __restrict__ accum) {
  int tid = threadIdx.x;
  float s0 = 0.f, s1 = 0.f;
  for (int i = tid; i < 1764; i += 256) s0 += dec3part[i];
  for (int i = tid; i < 1024; i += 256) s1 += vqpart[i];
  #pragma unroll
  for (int off = 32; off; off >>= 1) {
    s0 += __shfl_down(s0, off);
    s1 += __shfl_down(s1, off);
  }
  __shared__ float a0[4], a1[4];
  int lane = tid & 63, w = tid >> 6;
  if (lane == 0) { a0[w] = s0; a1[w] = s1; }
  __syncthreads();
  if (tid == 0) {
    accum[0] = a0[0] + a0[1] + a0[2] + a0[3];
    accum[1] = a1[0] + a1[1] + a1[2] + a1[3];
  }
}

// ---- FC1: hidden += quant_flat @ lw1 (k-split 4, 16-batch regs, atomics) --
__global__ __launch_bounds__(256) void fc1_k(
    const float* __restrict__ quant, const float* __restrict__ lw1,
    float* __restrict__ hidden) {
  int n = (blockIdx.x & 1) * 256 + threadIdx.x;
  int bg = (blockIdx.x >> 1) & 63;
  int ks = blockIdx.x >> 7;                // 0..3
  int b0 = bg * 16;
  const float* q0 = quant + (long)b0 * 4096 + ks * 1024;
  const float* w0 = lw1 + (long)ks * 1024 * 512 + n;
  float acc[16] = {};
  #pragma unroll 4
  for (int k = 0; k < 1024; ++k) {
    float wvv = w0[(long)k * 512];
    #pragma unroll
    for (int bb = 0; bb < 16; ++bb)
      acc[bb] = fmaf(q0[bb * 4096 + k], wvv, acc[bb]);
  }
  #pragma unroll
  for (int bb = 0; bb < 16; ++bb)
    atomicAdd(&hidden[(b0 + bb) * 512 + n], acc[bb]);
}

// ---- FC2: q_values = relu(hidden + lb1) @ lw2 + lb2; write losses ---------
__global__ __launch_bounds__(256) void fc2_k(
    const float* __restrict__ hidden, const float* __restrict__ lb1,
    const float* __restrict__ lw2, const float* __restrict__ lb2,
    const float* __restrict__ accum, float* __restrict__ out) {
  int t = blockIdx.x * 256 + threadIdx.x;  // 18432
  int b = t / 18, a = t % 18;
  const float* h = hidden + b * 512;
  float acc = lb2[a];
  #pragma unroll 4
  for (int n = 0; n < 512; ++n) {
    float hv = fmaxf(h[n] + lb1[n], 0.f);
    acc = fmaf(hv, lw2[n * 18 + a], acc);
  }
  out[t] = acc;
  if (t == 0) {
    out[18432] = accum[0] * (1.f / 28901376.f);          // /(1024*4*84*84)
    out[18433] = 1.25f * accum[1] * (1.f / 4194304.f);   // /(65536*64)
  }
}

extern "C" void kernel_launch(void* const* d_in, const int* in_sizes, int n_in,
                              void* d_out, int out_size, void* d_ws, size_t ws_size,
                              hipStream_t stream) {
  const float* x   = (const float*)d_in[0];
  const float* w1  = (const float*)d_in[1];
  const float* b1  = (const float*)d_in[2];
  const float* w2  = (const float*)d_in[3];
  const float* b2  = (const float*)d_in[4];
  const float* w3  = (const float*)d_in[5];
  const float* b3  = (const float*)d_in[6];
  const float* emb = (const float*)d_in[7];
  const float* dw1 = (const float*)d_in[8];
  const float* db1 = (const float*)d_in[9];
  const float* dw2 = (const float*)d_in[10];
  const float* db2 = (const float*)d_in[11];
  const float* dw3 = (const float*)d_in[12];
  const float* db3 = (const float*)d_in[13];
  const float* lw1 = (const float*)d_in[14];
  const float* lb1 = (const float*)d_in[15];
  const float* lw2 = (const float*)d_in[16];
  const float* lb2 = (const float*)d_in[17];

  float* ws = (float*)d_ws;
  float* h1     = ws;                    // 14450688 floats [B,32,21,21]
  float* h2     = ws + 14450688;         //  6553600 floats [B,64,10,10]
  float* enc    = ws + 21004288;         //  4194304 floats [B,64,8,8]
  float* quant  = ws + 25198592;         //  4194304 floats [B,64,8,8]
  float* d1     = h2;                    // reuse (h2 dead after conv3)
  float* d2b    = h1;                    // reuse (h1 dead after conv2)
  float* hidden = ws + 29392896;         //   524288 floats [B,512]
  float* accum  = ws + 29917184;         // [0]=rec sum, [1]=quant sum
  float* d3part = ws + 29917192;         // 1764 floats
  float* vqpart = ws + 29918956;         // 1024 floats
  float* outp   = (float*)d_out;

  zero_k<<<2048, 256, 0, stream>>>(hidden, accum);
  conv1_k<<<dim3(7056, 1), 256, 0, stream>>>(x, w1, b1, h1);
  conv2_k<<<1024, 256, 0, stream>>>(h1, w2, b2, h2);
  conv3_k<<<1024, 256, 0, stream>>>(h2, w3, b3, enc);
  vq_k<<<1024, 256, 0, stream>>>(enc, emb, quant, vqpart);
  dec1_k<<<1024, 256, 0, stream>>>(quant, dw1, db1, d1);
  dec2_k<<<1024, 256, 0, stream>>>(d1, dw2, db2, d2b);
  dec3_k<<<1764, 256, 0, stream>>>(d2b, dw3, db3, x, d3part);
  reduce_k<<<1, 256, 0, stream>>>(d3part, vqpart, accum);
  fc1_k<<<512, 256, 0, stream>>>(quant, lw1, hidden);
  fc2_k<<<72, 256, 0, stream>>>(hidden, lb1, lw2, lb2, accum, outp);
}